// Round 10
// baseline (284.395 us; speedup 1.0000x reference)
//
#include <hip/hip_runtime.h>
#include <hip/hip_bf16.h>
#include <math.h>

#define NT 2048
#define EMBD 512
#define NH 8
#define QKV_LD 1536

typedef unsigned short u16;
typedef __attribute__((ext_vector_type(8))) short short8;
typedef __attribute__((ext_vector_type(4))) float v4f;

static __device__ __forceinline__ float bf2f(unsigned int u) {
    union { unsigned int i; float f; } c; c.i = u << 16; return c.f;
}
static __device__ __forceinline__ unsigned int f2bf(float x) {   // RNE
    union { float f; unsigned int u; } c; c.f = x;
    return (c.u + 0x7fffu + ((c.u >> 16) & 1u)) >> 16;
}

// ------- split+transpose one 64x64 tile of W (device helper) ----------------
static __device__ __forceinline__ void split_wt_tile(const float* __restrict__ W,
    u16* __restrict__ wth, u16* __restrict__ wtl, int ld, int n0, int k0, int t)
{
    __shared__ float tile[64][65];
    const int r = t >> 2, c4 = (t & 3) << 4;
#pragma unroll
    for (int j = 0; j < 4; ++j)
        *(float4*)&tile[r][c4 + (j << 2)] =
            *(const float4*)(W + (size_t)(k0 + r) * ld + n0 + c4 + (j << 2));
    __syncthreads();
    const int n_l = t >> 2;
    u16 th[16], tl[16];
#pragma unroll
    for (int j = 0; j < 16; ++j) {
        float f = tile[c4 + j][n_l];
        unsigned int h = f2bf(f);
        th[j] = (u16)h;
        tl[j] = (u16)f2bf(f - bf2f(h));
    }
    u16* dh = wth + (size_t)(n0 + n_l) * EMBD + k0 + c4;
    u16* dl = wtl + (size_t)(n0 + n_l) * EMBD + k0 + c4;
    *(uint4*)dh       = *(uint4*)&th[0];
    *(uint4*)(dh + 8) = *(uint4*)&th[8];
    *(uint4*)dl       = *(uint4*)&tl[0];
    *(uint4*)(dl + 8) = *(uint4*)&tl[8];
}

// ------- prep: split x (blocks 0..1023), Wqkv^T (1024..1215), Wout^T (1216..1279)
__global__ __launch_bounds__(256) void prep(const float* __restrict__ x,
    const float* __restrict__ Wqkv, const float* __restrict__ Wout,
    u16* __restrict__ xh, u16* __restrict__ xl,
    u16* __restrict__ wth, u16* __restrict__ wtl,
    u16* __restrict__ woth, u16* __restrict__ wotl)
{
    const int b = blockIdx.x, t = threadIdx.x;
    if (b < 1024) {
        int i = (b * 256 + t) << 2;
        float4 v = *(const float4*)(x + i);
        float f[4] = {v.x, v.y, v.z, v.w};
        unsigned int hi[4], lo[4];
#pragma unroll
        for (int j = 0; j < 4; ++j) {
            hi[j] = f2bf(f[j]);
            lo[j] = f2bf(f[j] - bf2f(hi[j]));
        }
        uint2 wh; wh.x = hi[0] | (hi[1] << 16); wh.y = hi[2] | (hi[3] << 16);
        uint2 wl; wl.x = lo[0] | (lo[1] << 16); wl.y = lo[2] | (lo[3] << 16);
        *(uint2*)(xh + i) = wh;
        *(uint2*)(xl + i) = wl;
    } else if (b < 1216) {
        int bb = b - 1024;                    // 24 x 8
        split_wt_tile(Wqkv, wth, wtl, QKV_LD, (bb % 24) << 6, (bb / 24) << 6, t);
    } else {
        int bb = b - 1216;                    // 8 x 8
        split_wt_tile(Wout, woth, wotl, EMBD, (bb & 7) << 6, (bb >> 3) << 6, t);
    }
}

// ------- qkv = x @ Wqkv + b via split-precision bf16 MFMA -------------------
__global__ __launch_bounds__(256) void gemm_qkv_mfma(const u16* __restrict__ xh,
    const u16* __restrict__ xl, const u16* __restrict__ wth,
    const u16* __restrict__ wtl, const float* __restrict__ bias,
    u16* __restrict__ qkvb)
{
    const int n0 = blockIdx.x << 6, m0 = blockIdx.y << 6;
    const int w = threadIdx.x >> 6, lane = threadIdx.x & 63;
    const int wm = w >> 1, wn = w & 1;
    const int fr = lane & 15, kd = (lane >> 4) << 3;

    const u16* ah0 = xh + (size_t)(m0 + wm * 32 + fr) * EMBD + kd;
    const u16* al0 = xl + (size_t)(m0 + wm * 32 + fr) * EMBD + kd;
    const u16* bh0 = wth + (size_t)(n0 + wn * 32 + fr) * EMBD + kd;
    const u16* bl0 = wtl + (size_t)(n0 + wn * 32 + fr) * EMBD + kd;

    v4f acc[2][2] = {};
    for (int kc = 0; kc < EMBD; kc += 32) {
        short8 a_h[2], a_l[2], b_h[2], b_l[2];
#pragma unroll
        for (int im = 0; im < 2; ++im) {
            a_h[im] = *(const short8*)(ah0 + (size_t)im * 16 * EMBD + kc);
            a_l[im] = *(const short8*)(al0 + (size_t)im * 16 * EMBD + kc);
        }
#pragma unroll
        for (int in = 0; in < 2; ++in) {
            b_h[in] = *(const short8*)(bh0 + (size_t)in * 16 * EMBD + kc);
            b_l[in] = *(const short8*)(bl0 + (size_t)in * 16 * EMBD + kc);
        }
#pragma unroll
        for (int im = 0; im < 2; ++im)
#pragma unroll
            for (int in = 0; in < 2; ++in) {
                acc[im][in] = __builtin_amdgcn_mfma_f32_16x16x32_bf16(a_h[im], b_h[in], acc[im][in], 0, 0, 0);
                acc[im][in] = __builtin_amdgcn_mfma_f32_16x16x32_bf16(a_h[im], b_l[in], acc[im][in], 0, 0, 0);
                acc[im][in] = __builtin_amdgcn_mfma_f32_16x16x32_bf16(a_l[im], b_h[in], acc[im][in], 0, 0, 0);
            }
    }
    const int qr = (lane >> 4) << 2;
#pragma unroll
    for (int im = 0; im < 2; ++im)
#pragma unroll
        for (int in = 0; in < 2; ++in) {
            int n = n0 + wn * 32 + in * 16 + fr;
            float bv = bias[n];
#pragma unroll
            for (int r = 0; r < 4; ++r) {
                int m = m0 + wm * 32 + im * 16 + qr + r;
                qkvb[(size_t)m * QKV_LD + n] = (u16)f2bf(acc[im][in][r] + bv);
            }
        }
}

// ------- V transpose: Vt[h][t][k] <- qkv[k][h*192+128+t] ------------------
__global__ __launch_bounds__(256) void transpose_v(const u16* __restrict__ qkvb,
                                                   u16* __restrict__ Vt)
{
    __shared__ u16 tile[64][72];
    const int h = blockIdx.y, k0 = blockIdx.x << 6;
    const int t = threadIdx.x;
    {
        int r = t >> 2, cg = (t & 3) << 4;
        const u16* src = qkvb + (size_t)(k0 + r) * QKV_LD + h * 192 + 128 + cg;
        *(uint4*)&tile[r][cg]     = *(const uint4*)src;
        *(uint4*)&tile[r][cg + 8] = *(const uint4*)(src + 8);
    }
    __syncthreads();
    {
        int c = t >> 2, kg = (t & 3) << 4;
        u16 tmp[16];
#pragma unroll
        for (int j = 0; j < 16; ++j) tmp[j] = tile[kg + j][c];
        u16* dst = Vt + ((size_t)h * 64 + c) * NT + k0 + kg;
        *(uint4*)dst       = *(uint4*)&tmp[0];
        *(uint4*)(dst + 8) = *(uint4*)&tmp[8];
    }
}

// ---- bias matrix: bm[h][q][k] = bf16(bias(q,k)+bb[h]), triangle blocks -----
__global__ __launch_bounds__(256) void bias_mat(const float* __restrict__ vec,
    const float* __restrict__ Wb, const float* __restrict__ bb,
    u16* __restrict__ bm)
{
    __shared__ float flds[32];
    __shared__ float vql[96], vkl[96];
    __shared__ float bbl[8];
    __shared__ float ang_lds[1057];          // [qq*33 + kk]
    __shared__ float biasl[8 * 1057];        // [h*1057 + qq*33 + kk]

    const int t = threadIdx.x;
    int b = blockIdx.x, tq = 0, rem = 64;
    while (b >= rem) { b -= rem; ++tq; --rem; }
    const int tk = tq + b;
    const int q0 = tq << 5, k0 = tk << 5;

    if (t < 32) flds[t] = __fdiv_rn(__fdiv_rn((float)t, 31.0f), 0.1f);
    else if (t < 128) vql[t - 32] = vec[q0 * 3 + (t - 32)];
    else if (t < 224) vkl[t - 128] = vec[k0 * 3 + (t - 128)];
    else if (t < 232) bbl[t - 224] = bb[t - 224];
    __syncthreads();

    {   // phase 1a: angles (frozen numerics)
        const int qq = t & 31, kb = (t >> 5) << 2;
        const float a0 = vql[qq * 3], a1 = vql[qq * 3 + 1], a2 = vql[qq * 3 + 2];
#pragma unroll
        for (int j = 0; j < 4; ++j) {
            const int kk = kb + j;
            float c0 = vkl[kk * 3], c1 = vkl[kk * 3 + 1], c2 = vkl[kk * 3 + 2];
            float dot = __fadd_rn(__fadd_rn(__fmul_rn(a0, c0), __fmul_rn(a1, c1)),
                                  __fmul_rn(a2, c2));
            float dotc = fminf(fmaxf(dot, 0.0f), 1.0f);
            ang_lds[qq * 33 + kk] = __fdiv_rn(acosf(dotc), 0.001f);
        }
    }
    __syncthreads();

    {   // phase 1b: sincos features -> MFMA projection onto 8 heads
        const int w = t >> 6, lane = t & 63;
        const int fr = lane & 15, kd = (lane >> 4) << 3, qr = (lane >> 4) << 2;
        short8 BS, BC;
#pragma unroll
        for (int j = 0; j < 8; ++j) {
            float ws = (fr < 8) ? Wb[(kd + j) * 8 + fr] : 0.0f;
            float wc = (fr < 8) ? Wb[(32 + kd + j) * 8 + fr] : 0.0f;
            BS[j] = (short)f2bf(ws);
            BC[j] = (short)f2bf(wc);
        }
        for (int tt = w; tt < 64; tt += 4) {
            int p = (tt << 4) + fr;
            float ang = ang_lds[(p >> 5) * 33 + (p & 31)];
            short8 AS, AC;
#pragma unroll
            for (int j = 0; j < 8; ++j) {
                float ph = __fmul_rn(flds[kd + j], ang);
                float rv = ph * 0.15915494309189535f;
                float rf = rv - floorf(rv);
                AS[j] = (short)f2bf(__builtin_amdgcn_sinf(rf));
                AC[j] = (short)f2bf(__builtin_amdgcn_cosf(rf));
            }
            v4f c = {};
            c = __builtin_amdgcn_mfma_f32_16x16x32_bf16(AS, BS, c, 0, 0, 0);
            c = __builtin_amdgcn_mfma_f32_16x16x32_bf16(AC, BC, c, 0, 0, 0);
            if (fr < 8) {
#pragma unroll
                for (int r = 0; r < 4; ++r) {
                    int pp = (tt << 4) + qr + r;
                    biasl[fr * 1057 + (pp >> 5) * 33 + (pp & 31)] = c[r];
                }
            }
        }
    }
    __syncthreads();

    // phase 2: store both orientations, coalesced uint2 writes
    const int row = t >> 3, c4 = (t & 7) << 2;
#pragma unroll
    for (int h = 0; h < 8; ++h) {
        const float bv = bbl[h];
        unsigned int o[4];
#pragma unroll
        for (int j = 0; j < 4; ++j)
            o[j] = f2bf(biasl[h * 1057 + row * 33 + c4 + j] + bv);
        uint2 wv; wv.x = o[0] | (o[1] << 16); wv.y = o[2] | (o[3] << 16);
        *(uint2*)(bm + ((size_t)h * NT + q0 + row) * NT + k0 + c4) = wv;
    }
    if (tk != tq) {
#pragma unroll
        for (int h = 0; h < 8; ++h) {
            const float bv = bbl[h];
            unsigned int o[4];
#pragma unroll
            for (int j = 0; j < 4; ++j)
                o[j] = f2bf(biasl[h * 1057 + (c4 + j) * 33 + row] + bv);
            uint2 wv; wv.x = o[0] | (o[1] << 16); wv.y = o[2] | (o[3] << 16);
            *(uint2*)(bm + ((size_t)h * NT + k0 + row) * NT + q0 + c4) = wv;
        }
    }
}

// ------- bpart[z] = bm @ V via bf16 MFMA (split-K=2, 64-k unroll) -----------
__global__ __launch_bounds__(256) void biasv_mfma(const u16* __restrict__ bm,
    const u16* __restrict__ Vt, float* __restrict__ bpart)
{
    const int h = blockIdx.y, z = blockIdx.z;
    const int q0 = (blockIdx.x << 6) + ((threadIdx.x >> 6) << 4);
    const int lane = threadIdx.x & 63;
    const int fr = lane & 15;
    const int kd = (lane >> 4) << 3;
    const int kbase = z << 10;

    const u16* arow  = bm + (size_t)(h * NT + q0 + fr) * NT + kbase + kd;
    const u16* vbase = Vt + ((size_t)h * 64 + fr) * NT + kbase + kd;

    v4f c[4] = {};
    for (int ks = 0; ks < 1024; ks += 64) {
        short8 a0 = *(const short8*)(arow + ks);
        short8 a1 = *(const short8*)(arow + ks + 32);
#pragma unroll
        for (int nt = 0; nt < 4; ++nt) {
            short8 b0 = *(const short8*)(vbase + (size_t)nt * 16 * NT + ks);
            short8 b1 = *(const short8*)(vbase + (size_t)nt * 16 * NT + ks + 32);
            c[nt] = __builtin_amdgcn_mfma_f32_16x16x32_bf16(a0, b0, c[nt], 0, 0, 0);
            c[nt] = __builtin_amdgcn_mfma_f32_16x16x32_bf16(a1, b1, c[nt], 0, 0, 0);
        }
    }
    float* bp = bpart + (size_t)z * NT * EMBD;
    const int qr = (lane >> 4) << 2;
#pragma unroll
    for (int nt = 0; nt < 4; ++nt)
#pragma unroll
        for (int r = 0; r < 4; ++r)
            bp[(size_t)(q0 + qr + r) * EMBD + (h << 6) + (nt << 4) + fr] = c[nt][r];
}

// ------- flash term 1 v2: z=8, K-prefetch pipeline, wave-private P ----------
__global__ __launch_bounds__(256) void flash_attn(const u16* __restrict__ qkvb,
    const u16* __restrict__ Vt, u16* __restrict__ nump,
    float* __restrict__ zpart)
{
    __shared__ u16 P[4][16][40];
    const int h = blockIdx.y, z = blockIdx.z;
    const int w = threadIdx.x >> 6, lane = threadIdx.x & 63;
    const int fr = lane & 15, kd = (lane >> 4) << 3, qr = (lane >> 4) << 2;
    const int q0 = (blockIdx.x << 6) + (w << 4);
    const int kbase = z << 8;                // 256-wide k strip

    const u16* qb = qkvb + (size_t)(q0 + fr) * QKV_LD + h * 192 + kd;
    short8 qa0 = *(const short8*)(qb);
    short8 qa1 = *(const short8*)(qb + 32);
    const u16* kbp = qkvb + (size_t)kbase * QKV_LD + h * 192 + 64 + kd;
    const u16* vb  = Vt + ((size_t)h * 64 + fr) * NT + kbase + kd;

    // prefetch K tile 0 (rows fr, 16+fr of the strip)
    short8 k0a, k0b, k1a, k1b;
    {
        const u16* kr0 = kbp + (size_t)fr * QKV_LD;
        const u16* kr1 = kbp + (size_t)(16 + fr) * QKV_LD;
        k0a = *(const short8*)(kr0); k0b = *(const short8*)(kr0 + 32);
        k1a = *(const short8*)(kr1); k1b = *(const short8*)(kr1 + 32);
    }
    v4f acc[4] = {};
    float zac[4] = {};
    for (int kt = 0; kt < 256; kt += 32) {
        short8 ck0a = k0a, ck0b = k0b, ck1a = k1a, ck1b = k1b;
        if (kt + 32 < 256) {                 // prefetch next K tile
            const u16* kr0 = kbp + (size_t)(kt + 32 + fr) * QKV_LD;
            const u16* kr1 = kbp + (size_t)(kt + 48 + fr) * QKV_LD;
            k0a = *(const short8*)(kr0); k0b = *(const short8*)(kr0 + 32);
            k1a = *(const short8*)(kr1); k1b = *(const short8*)(kr1 + 32);
        }
        // V frags for this tile (issued early, consumed after P)
        short8 v0 = *(const short8*)(vb + (size_t)0 * 16 * NT + kt);
        short8 v1 = *(const short8*)(vb + (size_t)1 * 16 * NT + kt);
        short8 v2 = *(const short8*)(vb + (size_t)2 * 16 * NT + kt);
        short8 v3 = *(const short8*)(vb + (size_t)3 * 16 * NT + kt);
        // scores for 16 q x 32 k
        v4f c0 = {}, c1 = {};
        c0 = __builtin_amdgcn_mfma_f32_16x16x32_bf16(qa0, ck0a, c0, 0, 0, 0);
        c0 = __builtin_amdgcn_mfma_f32_16x16x32_bf16(qa1, ck0b, c0, 0, 0, 0);
        c1 = __builtin_amdgcn_mfma_f32_16x16x32_bf16(qa0, ck1a, c1, 0, 0, 0);
        c1 = __builtin_amdgcn_mfma_f32_16x16x32_bf16(qa1, ck1b, c1, 0, 0, 0);
#pragma unroll
        for (int r = 0; r < 4; ++r) {
            float e0 = __expf(c0[r] * 0.125f);
            float e1 = __expf(c1[r] * 0.125f);
            zac[r] += e0 + e1;
            P[w][qr + r][fr]      = (u16)f2bf(e0);
            P[w][qr + r][16 + fr] = (u16)f2bf(e1);
        }
        union { uint2 u2[2]; short8 s8; } pa;
        pa.u2[0] = *(uint2*)&P[w][fr][kd];
        pa.u2[1] = *(uint2*)&P[w][fr][kd + 4];
        acc[0] = __builtin_amdgcn_mfma_f32_16x16x32_bf16(pa.s8, v0, acc[0], 0, 0, 0);
        acc[1] = __builtin_amdgcn_mfma_f32_16x16x32_bf16(pa.s8, v1, acc[1], 0, 0, 0);
        acc[2] = __builtin_amdgcn_mfma_f32_16x16x32_bf16(pa.s8, v2, acc[2], 0, 0, 0);
        acc[3] = __builtin_amdgcn_mfma_f32_16x16x32_bf16(pa.s8, v3, acc[3], 0, 0, 0);
    }
#pragma unroll
    for (int off = 1; off < 16; off <<= 1)
#pragma unroll
        for (int r = 0; r < 4; ++r) zac[r] += __shfl_xor(zac[r], off);
    if (fr == 0) {
#pragma unroll
        for (int r = 0; r < 4; ++r)
            zpart[((size_t)z * NH + h) * NT + q0 + qr + r] = zac[r];
    }
    u16* np = nump + (size_t)z * NT * EMBD;
#pragma unroll
    for (int ti = 0; ti < 4; ++ti)
#pragma unroll
        for (int r = 0; r < 4; ++r)
            np[(size_t)(q0 + qr + r) * EMBD + (h << 6) + (ti << 4) + fr] =
                (u16)f2bf(acc[ti][r]);
}

// ------- combine: y = (sum_z nump)/(sum_z zpart) + sum_z bpart -> yh/yl -----
__global__ __launch_bounds__(256) void combine_emit(const u16* __restrict__ nump,
    const float* __restrict__ zpart, const float* __restrict__ bpart,
    u16* __restrict__ yh, u16* __restrict__ yl)
{
    const int MN = NT * EMBD;
    int i = (blockIdx.x * 256 + threadIdx.x) << 2;
    const int q = i >> 9, h = (i & 511) >> 6;
    float zs = 0.f;
#pragma unroll
    for (int z = 0; z < 8; ++z) zs += zpart[((size_t)z * NH + h) * NT + q];
    const float inv = 1.0f / zs;
    float a[4] = {};
#pragma unroll
    for (int z = 0; z < 8; ++z) {
        uint2 r = *(const uint2*)(nump + (size_t)z * MN + i);
        a[0] += bf2f(r.x & 0xffffu); a[1] += bf2f(r.x >> 16);
        a[2] += bf2f(r.y & 0xffffu); a[3] += bf2f(r.y >> 16);
    }
    float bsum[4] = {};
#pragma unroll
    for (int z = 0; z < 2; ++z) {
        float4 p = *(const float4*)(bpart + (size_t)z * MN + i);
        bsum[0] += p.x; bsum[1] += p.y; bsum[2] += p.z; bsum[3] += p.w;
    }
    unsigned int hi[4], lo[4];
#pragma unroll
    for (int j = 0; j < 4; ++j) {
        float y = a[j] * inv + bsum[j];
        hi[j] = f2bf(y);
        lo[j] = f2bf(y - bf2f(hi[j]));
    }
    uint2 wh; wh.x = hi[0] | (hi[1] << 16); wh.y = hi[2] | (hi[3] << 16);
    uint2 wl; wl.x = lo[0] | (lo[1] << 16); wl.y = lo[2] | (lo[3] << 16);
    *(uint2*)(yh + i) = wh;
    *(uint2*)(yl + i) = wl;
}

// ------- out = y @ Wout + bout via split-precision bf16 MFMA ----------------
__global__ __launch_bounds__(256) void gemm_out_mfma(const u16* __restrict__ yh,
    const u16* __restrict__ yl, const u16* __restrict__ wh,
    const u16* __restrict__ wl, const float* __restrict__ bias,
    float* __restrict__ out)
{
    const int n0 = blockIdx.x << 6, m0 = blockIdx.y << 6;
    const int w = threadIdx.x >> 6, lane = threadIdx.x & 63;
    const int wm = w >> 1, wn = w & 1;
    const int fr = lane & 15, kd = (lane >> 4) << 3;

    const u16* ah0 = yh + (size_t)(m0 + wm * 32 + fr) * EMBD + kd;
    const u16* al0 = yl + (size_t)(m0 + wm * 32 + fr) * EMBD + kd;
    const u16* bh0 = wh + (size_t)(n0 + wn * 32 + fr) * EMBD + kd;
    const u16* bl0 = wl + (size_t)(n0 + wn * 32 + fr) * EMBD + kd;

    v4f acc[2][2] = {};
    for (int kc = 0; kc < EMBD; kc += 32) {
        short8 a_h[2], a_l[2], b_h[2], b_l[2];
#pragma unroll
        for (int im = 0; im < 2; ++im) {
            a_h[im] = *(const short8*)(ah0 + (size_t)im * 16 * EMBD + kc);
            a_l[im] = *(const short8*)(al0 + (size_t)im * 16 * EMBD + kc);
        }
#pragma unroll
        for (int in = 0; in < 2; ++in) {
            b_h[in] = *(const short8*)(bh0 + (size_t)in * 16 * EMBD + kc);
            b_l[in] = *(const short8*)(bl0 + (size_t)in * 16 * EMBD + kc);
        }
#pragma unroll
        for (int im = 0; im < 2; ++im)
#pragma unroll
            for (int in = 0; in < 2; ++in) {
                acc[im][in] = __builtin_amdgcn_mfma_f32_16x16x32_bf16(a_h[im], b_h[in], acc[im][in], 0, 0, 0);
                acc[im][in] = __builtin_amdgcn_mfma_f32_16x16x32_bf16(a_h[im], b_l[in], acc[im][in], 0, 0, 0);
                acc[im][in] = __builtin_amdgcn_mfma_f32_16x16x32_bf16(a_l[im], b_h[in], acc[im][in], 0, 0, 0);
            }
    }
    const int qr = (lane >> 4) << 2;
#pragma unroll
    for (int im = 0; im < 2; ++im)
#pragma unroll
        for (int in = 0; in < 2; ++in) {
            int n = n0 + wn * 32 + in * 16 + fr;
            float bv = bias[n];
#pragma unroll
            for (int r = 0; r < 4; ++r) {
                int m = m0 + wm * 32 + im * 16 + qr + r;
                out[(size_t)m * EMBD + n] = acc[im][in][r] + bv;
            }
        }
}

extern "C" void kernel_launch(void* const* d_in, const int* in_sizes, int n_in,
                              void* d_out, int out_size, void* d_ws, size_t ws_size,
                              hipStream_t stream)
{
    const float* x    = (const float*)d_in[0];
    const float* vec  = (const float*)d_in[1];
    const float* Wqkv = (const float*)d_in[2];
    const float* bqkv = (const float*)d_in[3];
    const float* Wb   = (const float*)d_in[4];
    const float* bb   = (const float*)d_in[5];
    const float* Wout = (const float*)d_in[6];
    const float* bout = (const float*)d_in[7];
    float* out = (float*)d_out;

    char* ws = (char*)d_ws;
    u16*   qkvb  = (u16*)(ws);                      //  6,291,456
    u16*   Vt    = (u16*)(ws + 6291456);            //  2,097,152
    float* zpart = (float*)(ws + 8388608);          //    524,288 (8 z-parts)
    float* bpart = (float*)(ws + 8912896);          //  8,388,608 (2 z-parts f32)
    u16*   yh    = (u16*)(ws + 17301504);           //  2,097,152
    u16*   yl    = (u16*)(ws + 19398656);           //  2,097,152
    u16*   woth  = (u16*)(ws + 21495808);           //    524,288 (persistent)
    u16*   wotl  = (u16*)(ws + 22020096);           //    524,288
    char*  big   = ws + 22544384;                   // 67,108,864 shared region
    // big region lifetimes (sequenced by launch order):
    u16*   xh    = (u16*)(big);                     // prep -> gemm_qkv
    u16*   xl    = (u16*)(big + 2097152);
    u16*   wth   = (u16*)(big + 4194304);
    u16*   wtl   = (u16*)(big + 5767168);
    u16*   bm    = (u16*)(big);                     // bias_mat -> biasv
    u16*   nump  = (u16*)(big);                     // flash -> combine (16.8MB)
    // total: 89,653,248 B

    prep<<<1280, 256, 0, stream>>>(x, Wqkv, Wout, xh, xl, wth, wtl, woth, wotl);
    gemm_qkv_mfma<<<dim3(24, 32), 256, 0, stream>>>(xh, xl, wth, wtl, bqkv, qkvb);
    transpose_v<<<dim3(32, 8), 256, 0, stream>>>(qkvb, Vt);
    bias_mat<<<2080, 256, 0, stream>>>(vec, Wb, bb, bm);
    biasv_mfma<<<dim3(32, 8, 2), 256, 0, stream>>>(bm, Vt, bpart);
    flash_attn<<<dim3(32, 8, 8), 256, 0, stream>>>(qkvb, Vt, nump, zpart);
    combine_emit<<<1024, 256, 0, stream>>>(nump, zpart, bpart, yh, yl);
    gemm_out_mfma<<<dim3(8, 32), 256, 0, stream>>>(yh, yl, woth, wotl, bout, out);
}

// Round 11
// 281.870 us; speedup vs baseline: 1.0090x; 1.0090x over previous
//
#include <hip/hip_runtime.h>
#include <hip/hip_bf16.h>
#include <math.h>

#define NT 2048
#define EMBD 512
#define NH 8
#define QKV_LD 1536

typedef unsigned short u16;
typedef __attribute__((ext_vector_type(8))) short short8;
typedef __attribute__((ext_vector_type(4))) float v4f;

static __device__ __forceinline__ float bf2f(unsigned int u) {
    union { unsigned int i; float f; } c; c.i = u << 16; return c.f;
}
static __device__ __forceinline__ unsigned int f2bf(float x) {   // RNE
    union { float f; unsigned int u; } c; c.f = x;
    return (c.u + 0x7fffu + ((c.u >> 16) & 1u)) >> 16;
}

// ------- split+transpose one 64x64 tile of W (device helper) ----------------
static __device__ __forceinline__ void split_wt_tile(const float* __restrict__ W,
    u16* __restrict__ wth, u16* __restrict__ wtl, int ld, int n0, int k0, int t)
{
    __shared__ float tile[64][65];
    const int r = t >> 2, c4 = (t & 3) << 4;
#pragma unroll
    for (int j = 0; j < 4; ++j)
        *(float4*)&tile[r][c4 + (j << 2)] =
            *(const float4*)(W + (size_t)(k0 + r) * ld + n0 + c4 + (j << 2));
    __syncthreads();
    const int n_l = t >> 2;
    u16 th[16], tl[16];
#pragma unroll
    for (int j = 0; j < 16; ++j) {
        float f = tile[c4 + j][n_l];
        unsigned int h = f2bf(f);
        th[j] = (u16)h;
        tl[j] = (u16)f2bf(f - bf2f(h));
    }
    u16* dh = wth + (size_t)(n0 + n_l) * EMBD + k0 + c4;
    u16* dl = wtl + (size_t)(n0 + n_l) * EMBD + k0 + c4;
    *(uint4*)dh       = *(uint4*)&th[0];
    *(uint4*)(dh + 8) = *(uint4*)&th[8];
    *(uint4*)dl       = *(uint4*)&tl[0];
    *(uint4*)(dl + 8) = *(uint4*)&tl[8];
}

// ------- prep: split x (0..1023), Wqkv^T (1024..1215), Wout^T (1216..1279) --
__global__ __launch_bounds__(256) void prep(const float* __restrict__ x,
    const float* __restrict__ Wqkv, const float* __restrict__ Wout,
    u16* __restrict__ xh, u16* __restrict__ xl,
    u16* __restrict__ wth, u16* __restrict__ wtl,
    u16* __restrict__ woth, u16* __restrict__ wotl)
{
    const int b = blockIdx.x, t = threadIdx.x;
    if (b < 1024) {
        int i = (b * 256 + t) << 2;
        float4 v = *(const float4*)(x + i);
        float f[4] = {v.x, v.y, v.z, v.w};
        unsigned int hi[4], lo[4];
#pragma unroll
        for (int j = 0; j < 4; ++j) {
            hi[j] = f2bf(f[j]);
            lo[j] = f2bf(f[j] - bf2f(hi[j]));
        }
        uint2 wh; wh.x = hi[0] | (hi[1] << 16); wh.y = hi[2] | (hi[3] << 16);
        uint2 wl; wl.x = lo[0] | (lo[1] << 16); wl.y = lo[2] | (lo[3] << 16);
        *(uint2*)(xh + i) = wh;
        *(uint2*)(xl + i) = wl;
    } else if (b < 1216) {
        int bb = b - 1024;                    // 24 x 8
        split_wt_tile(Wqkv, wth, wtl, QKV_LD, (bb % 24) << 6, (bb / 24) << 6, t);
    } else {
        int bb = b - 1216;                    // 8 x 8
        split_wt_tile(Wout, woth, wotl, EMBD, (bb & 7) << 6, (bb >> 3) << 6, t);
    }
}

// ------- qkv = x @ Wqkv + b (split bf16 MFMA); V-tiles routed to Vt ---------
__global__ __launch_bounds__(256) void gemm_qkv_mfma(const u16* __restrict__ xh,
    const u16* __restrict__ xl, const u16* __restrict__ wth,
    const u16* __restrict__ wtl, const float* __restrict__ bias,
    u16* __restrict__ qkvb, u16* __restrict__ Vt)
{
    __shared__ u16 vtile[64][72];
    const int bn = blockIdx.x;
    const int n0 = bn << 6, m0 = blockIdx.y << 6;
    const int t = threadIdx.x;
    const int w = t >> 6, lane = t & 63;
    const int wm = w >> 1, wn = w & 1;
    const int fr = lane & 15, kd = (lane >> 4) << 3;

    const u16* ah0 = xh + (size_t)(m0 + wm * 32 + fr) * EMBD + kd;
    const u16* al0 = xl + (size_t)(m0 + wm * 32 + fr) * EMBD + kd;
    const u16* bh0 = wth + (size_t)(n0 + wn * 32 + fr) * EMBD + kd;
    const u16* bl0 = wtl + (size_t)(n0 + wn * 32 + fr) * EMBD + kd;

    v4f acc[2][2] = {};
    for (int kc = 0; kc < EMBD; kc += 32) {
        short8 a_h[2], a_l[2], b_h[2], b_l[2];
#pragma unroll
        for (int im = 0; im < 2; ++im) {
            a_h[im] = *(const short8*)(ah0 + (size_t)im * 16 * EMBD + kc);
            a_l[im] = *(const short8*)(al0 + (size_t)im * 16 * EMBD + kc);
        }
#pragma unroll
        for (int in = 0; in < 2; ++in) {
            b_h[in] = *(const short8*)(bh0 + (size_t)in * 16 * EMBD + kc);
            b_l[in] = *(const short8*)(bl0 + (size_t)in * 16 * EMBD + kc);
        }
#pragma unroll
        for (int im = 0; im < 2; ++im)
#pragma unroll
            for (int in = 0; in < 2; ++in) {
                acc[im][in] = __builtin_amdgcn_mfma_f32_16x16x32_bf16(a_h[im], b_h[in], acc[im][in], 0, 0, 0);
                acc[im][in] = __builtin_amdgcn_mfma_f32_16x16x32_bf16(a_h[im], b_l[in], acc[im][in], 0, 0, 0);
                acc[im][in] = __builtin_amdgcn_mfma_f32_16x16x32_bf16(a_l[im], b_h[in], acc[im][in], 0, 0, 0);
            }
    }
    const int qr = (lane >> 4) << 2;
    if (bn % 3 != 2) {
        // Q/K tile: store to qkvb as before
#pragma unroll
        for (int im = 0; im < 2; ++im)
#pragma unroll
            for (int in = 0; in < 2; ++in) {
                int n = n0 + wn * 32 + in * 16 + fr;
                float bv = bias[n];
#pragma unroll
                for (int r = 0; r < 4; ++r) {
                    int m = m0 + wm * 32 + im * 16 + qr + r;
                    qkvb[(size_t)m * QKV_LD + n] = (u16)f2bf(acc[im][in][r] + bv);
                }
            }
    } else {
        // V tile: transpose in LDS, write Vt[h][t][k] coalesced
        const int h = bn / 3;
#pragma unroll
        for (int im = 0; im < 2; ++im)
#pragma unroll
            for (int in = 0; in < 2; ++in) {
                int nl = wn * 32 + in * 16 + fr;
                float bv = bias[n0 + nl];
#pragma unroll
                for (int r = 0; r < 4; ++r)
                    vtile[wm * 32 + im * 16 + qr + r][nl] =
                        (u16)f2bf(acc[im][in][r] + bv);
            }
        __syncthreads();
        const int c = t >> 2, kg = (t & 3) << 4;
        u16 tmp[16];
#pragma unroll
        for (int j = 0; j < 16; ++j) tmp[j] = vtile[kg + j][c];
        u16* dst = Vt + ((size_t)h * 64 + c) * NT + m0 + kg;
        *(uint4*)dst       = *(uint4*)&tmp[0];
        *(uint4*)(dst + 8) = *(uint4*)&tmp[8];
    }
}

// ---- bias matrix: bm[h][q][k] = bf16(bias(q,k)+bb[h]), triangle blocks -----
// Frozen angle/sincos numerics. bb folded into MFMA acc init; biasl stored
// bf16 (21.7KB LDS total -> 7 blocks/CU vs 4).
__global__ __launch_bounds__(256) void bias_mat(const float* __restrict__ vec,
    const float* __restrict__ Wb, const float* __restrict__ bb,
    u16* __restrict__ bm)
{
    __shared__ float flds[32];
    __shared__ float vql[96], vkl[96];
    __shared__ float bbl[8];
    __shared__ float ang_lds[1057];          // [qq*33 + kk]
    __shared__ u16 biaslu[8 * 1057];         // bf16 bias+bb, strides 1057/33

    const int t = threadIdx.x;
    int b = blockIdx.x, tq = 0, rem = 64;
    while (b >= rem) { b -= rem; ++tq; --rem; }
    const int tk = tq + b;
    const int q0 = tq << 5, k0 = tk << 5;

    if (t < 32) flds[t] = __fdiv_rn(__fdiv_rn((float)t, 31.0f), 0.1f);
    else if (t < 128) vql[t - 32] = vec[q0 * 3 + (t - 32)];
    else if (t < 224) vkl[t - 128] = vec[k0 * 3 + (t - 128)];
    else if (t < 232) bbl[t - 224] = bb[t - 224];
    __syncthreads();

    {   // phase 1a: angles (frozen numerics)
        const int qq = t & 31, kb = (t >> 5) << 2;
        const float a0 = vql[qq * 3], a1 = vql[qq * 3 + 1], a2 = vql[qq * 3 + 2];
#pragma unroll
        for (int j = 0; j < 4; ++j) {
            const int kk = kb + j;
            float c0 = vkl[kk * 3], c1 = vkl[kk * 3 + 1], c2 = vkl[kk * 3 + 2];
            float dot = __fadd_rn(__fadd_rn(__fmul_rn(a0, c0), __fmul_rn(a1, c1)),
                                  __fmul_rn(a2, c2));
            float dotc = fminf(fmaxf(dot, 0.0f), 1.0f);
            ang_lds[qq * 33 + kk] = __fdiv_rn(acosf(dotc), 0.001f);
        }
    }
    __syncthreads();

    {   // phase 1b: sincos features -> MFMA projection (+bb via acc init)
        const int w = t >> 6, lane = t & 63;
        const int fr = lane & 15, kd = (lane >> 4) << 3, qr = (lane >> 4) << 2;
        short8 BS, BC;
#pragma unroll
        for (int j = 0; j < 8; ++j) {
            float ws = (fr < 8) ? Wb[(kd + j) * 8 + fr] : 0.0f;
            float wc = (fr < 8) ? Wb[(32 + kd + j) * 8 + fr] : 0.0f;
            BS[j] = (short)f2bf(ws);
            BC[j] = (short)f2bf(wc);
        }
        const float bb0 = (fr < 8) ? bbl[fr] : 0.0f;
        for (int tt = w; tt < 64; tt += 4) {
            int p = (tt << 4) + fr;
            float ang = ang_lds[(p >> 5) * 33 + (p & 31)];
            short8 AS, AC;
#pragma unroll
            for (int j = 0; j < 8; ++j) {
                float ph = __fmul_rn(flds[kd + j], ang);
                float rv = ph * 0.15915494309189535f;
                float rf = rv - floorf(rv);
                AS[j] = (short)f2bf(__builtin_amdgcn_sinf(rf));
                AC[j] = (short)f2bf(__builtin_amdgcn_cosf(rf));
            }
            v4f c = {bb0, bb0, bb0, bb0};
            c = __builtin_amdgcn_mfma_f32_16x16x32_bf16(AS, BS, c, 0, 0, 0);
            c = __builtin_amdgcn_mfma_f32_16x16x32_bf16(AC, BC, c, 0, 0, 0);
            if (fr < 8) {
#pragma unroll
                for (int r = 0; r < 4; ++r) {
                    int pp = (tt << 4) + qr + r;
                    biaslu[fr * 1057 + (pp >> 5) * 33 + (pp & 31)] = (u16)f2bf(c[r]);
                }
            }
        }
    }
    __syncthreads();

    // phase 2: pure LDS -> global copy, both orientations, coalesced uint2
    const int row = t >> 3, c4 = (t & 7) << 2;
#pragma unroll
    for (int h = 0; h < 8; ++h) {
        unsigned int o[4];
#pragma unroll
        for (int j = 0; j < 4; ++j)
            o[j] = biaslu[h * 1057 + row * 33 + c4 + j];
        uint2 wv; wv.x = o[0] | (o[1] << 16); wv.y = o[2] | (o[3] << 16);
        *(uint2*)(bm + ((size_t)h * NT + q0 + row) * NT + k0 + c4) = wv;
    }
    if (tk != tq) {
#pragma unroll
        for (int h = 0; h < 8; ++h) {
            unsigned int o[4];
#pragma unroll
            for (int j = 0; j < 4; ++j)
                o[j] = biaslu[h * 1057 + (c4 + j) * 33 + row];
            uint2 wv; wv.x = o[0] | (o[1] << 16); wv.y = o[2] | (o[3] << 16);
            *(uint2*)(bm + ((size_t)h * NT + k0 + row) * NT + q0 + c4) = wv;
        }
    }
}

// ------- bpart[z] = bm @ V via bf16 MFMA (split-K=4, 64-k unroll) -----------
__global__ __launch_bounds__(256) void biasv_mfma(const u16* __restrict__ bm,
    const u16* __restrict__ Vt, float* __restrict__ bpart)
{
    const int h = blockIdx.y, z = blockIdx.z;
    const int q0 = (blockIdx.x << 6) + ((threadIdx.x >> 6) << 4);
    const int lane = threadIdx.x & 63;
    const int fr = lane & 15;
    const int kd = (lane >> 4) << 3;
    const int kbase = z << 9;

    const u16* arow  = bm + (size_t)(h * NT + q0 + fr) * NT + kbase + kd;
    const u16* vbase = Vt + ((size_t)h * 64 + fr) * NT + kbase + kd;

    v4f c[4] = {};
    for (int ks = 0; ks < 512; ks += 64) {
        short8 a0 = *(const short8*)(arow + ks);
        short8 a1 = *(const short8*)(arow + ks + 32);
#pragma unroll
        for (int nt = 0; nt < 4; ++nt) {
            short8 b0 = *(const short8*)(vbase + (size_t)nt * 16 * NT + ks);
            short8 b1 = *(const short8*)(vbase + (size_t)nt * 16 * NT + ks + 32);
            c[nt] = __builtin_amdgcn_mfma_f32_16x16x32_bf16(a0, b0, c[nt], 0, 0, 0);
            c[nt] = __builtin_amdgcn_mfma_f32_16x16x32_bf16(a1, b1, c[nt], 0, 0, 0);
        }
    }
    float* bp = bpart + (size_t)z * NT * EMBD;
    const int qr = (lane >> 4) << 2;
#pragma unroll
    for (int nt = 0; nt < 4; ++nt)
#pragma unroll
        for (int r = 0; r < 4; ++r)
            bp[(size_t)(q0 + qr + r) * EMBD + (h << 6) + (nt << 4) + fr] = c[nt][r];
}

// ------- flash term 1 (R9 measured config): z=4, dbuf wave-private P --------
__global__ __launch_bounds__(256) void flash_attn(const u16* __restrict__ qkvb,
    const u16* __restrict__ Vt, u16* __restrict__ nump,
    float* __restrict__ zpart)
{
    __shared__ u16 P[4][2][16][40];
    const int h = blockIdx.y, z = blockIdx.z;
    const int w = threadIdx.x >> 6, lane = threadIdx.x & 63;
    const int fr = lane & 15, kd = (lane >> 4) << 3, qr = (lane >> 4) << 2;
    const int q0 = (blockIdx.x << 6) + (w << 4);
    const int kbase = z << 9;

    const u16* qb = qkvb + (size_t)(q0 + fr) * QKV_LD + h * 192 + kd;
    short8 qa0 = *(const short8*)(qb);
    short8 qa1 = *(const short8*)(qb + 32);
    const u16* kbp = qkvb + (size_t)kbase * QKV_LD + h * 192 + 64 + kd;
    const u16* vb  = Vt + ((size_t)h * 64 + fr) * NT + kbase + kd;

    v4f acc[4] = {};
    float zac[4] = {};
    int buf = 0;
    for (int kt = 0; kt < 512; kt += 32) {
#pragma unroll
        for (int ks = 0; ks < 2; ++ks) {
            const u16* kr = kbp + (size_t)(kt + ks * 16 + fr) * QKV_LD;
            short8 kb0 = *(const short8*)(kr);
            short8 kb1 = *(const short8*)(kr + 32);
            v4f c = {};
            c = __builtin_amdgcn_mfma_f32_16x16x32_bf16(qa0, kb0, c, 0, 0, 0);
            c = __builtin_amdgcn_mfma_f32_16x16x32_bf16(qa1, kb1, c, 0, 0, 0);
#pragma unroll
            for (int r = 0; r < 4; ++r) {
                float ex = __expf(c[r] * 0.125f);
                zac[r] += ex;
                P[w][buf][qr + r][ks * 16 + fr] = (u16)f2bf(ex);
            }
        }
        union { uint2 u2[2]; short8 s8; } pa;
        pa.u2[0] = *(uint2*)&P[w][buf][fr][kd];
        pa.u2[1] = *(uint2*)&P[w][buf][fr][kd + 4];
#pragma unroll
        for (int ti = 0; ti < 4; ++ti) {
            short8 bfr = *(const short8*)(vb + (size_t)(ti * 16) * NT + kt);
            acc[ti] = __builtin_amdgcn_mfma_f32_16x16x32_bf16(pa.s8, bfr, acc[ti], 0, 0, 0);
        }
        buf ^= 1;
    }
#pragma unroll
    for (int off = 1; off < 16; off <<= 1)
#pragma unroll
        for (int r = 0; r < 4; ++r) zac[r] += __shfl_xor(zac[r], off);
    if (fr == 0) {
#pragma unroll
        for (int r = 0; r < 4; ++r)
            zpart[((size_t)z * NH + h) * NT + q0 + qr + r] = zac[r];
    }
    u16* np = nump + (size_t)z * NT * EMBD;
#pragma unroll
    for (int ti = 0; ti < 4; ++ti)
#pragma unroll
        for (int r = 0; r < 4; ++r)
            np[(size_t)(q0 + qr + r) * EMBD + (h << 6) + (ti << 4) + fr] =
                (u16)f2bf(acc[ti][r]);
}

// ------- combine: y = (sum_z nump)/(sum_z zpart) + sum_z bpart -> yh/yl -----
__global__ __launch_bounds__(256) void combine_emit(const u16* __restrict__ nump,
    const float* __restrict__ zpart, const float* __restrict__ bpart,
    u16* __restrict__ yh, u16* __restrict__ yl)
{
    const int MN = NT * EMBD;
    int i = (blockIdx.x * 256 + threadIdx.x) << 2;
    const int q = i >> 9, h = (i & 511) >> 6;
    float zs = 0.f;
#pragma unroll
    for (int z = 0; z < 4; ++z) zs += zpart[((size_t)z * NH + h) * NT + q];
    const float inv = 1.0f / zs;
    float a[4] = {};
#pragma unroll
    for (int z = 0; z < 4; ++z) {
        uint2 r = *(const uint2*)(nump + (size_t)z * MN + i);
        a[0] += bf2f(r.x & 0xffffu); a[1] += bf2f(r.x >> 16);
        a[2] += bf2f(r.y & 0xffffu); a[3] += bf2f(r.y >> 16);
    }
    float bsum[4] = {};
#pragma unroll
    for (int z = 0; z < 4; ++z) {
        float4 p = *(const float4*)(bpart + (size_t)z * MN + i);
        bsum[0] += p.x; bsum[1] += p.y; bsum[2] += p.z; bsum[3] += p.w;
    }
    unsigned int hi[4], lo[4];
#pragma unroll
    for (int j = 0; j < 4; ++j) {
        float y = a[j] * inv + bsum[j];
        hi[j] = f2bf(y);
        lo[j] = f2bf(y - bf2f(hi[j]));
    }
    uint2 wh; wh.x = hi[0] | (hi[1] << 16); wh.y = hi[2] | (hi[3] << 16);
    uint2 wl; wl.x = lo[0] | (lo[1] << 16); wl.y = lo[2] | (lo[3] << 16);
    *(uint2*)(yh + i) = wh;
    *(uint2*)(yl + i) = wl;
}

// ------- out = y @ Wout + bout via split-precision bf16 MFMA ----------------
__global__ __launch_bounds__(256) void gemm_out_mfma(const u16* __restrict__ yh,
    const u16* __restrict__ yl, const u16* __restrict__ wh,
    const u16* __restrict__ wl, const float* __restrict__ bias,
    float* __restrict__ out)
{
    const int n0 = blockIdx.x << 6, m0 = blockIdx.y << 6;
    const int w = threadIdx.x >> 6, lane = threadIdx.x & 63;
    const int wm = w >> 1, wn = w & 1;
    const int fr = lane & 15, kd = (lane >> 4) << 3;

    const u16* ah0 = yh + (size_t)(m0 + wm * 32 + fr) * EMBD + kd;
    const u16* al0 = yl + (size_t)(m0 + wm * 32 + fr) * EMBD + kd;
    const u16* bh0 = wh + (size_t)(n0 + wn * 32 + fr) * EMBD + kd;
    const u16* bl0 = wl + (size_t)(n0 + wn * 32 + fr) * EMBD + kd;

    v4f acc[2][2] = {};
    for (int kc = 0; kc < EMBD; kc += 32) {
        short8 a_h[2], a_l[2], b_h[2], b_l[2];
#pragma unroll
        for (int im = 0; im < 2; ++im) {
            a_h[im] = *(const short8*)(ah0 + (size_t)im * 16 * EMBD + kc);
            a_l[im] = *(const short8*)(al0 + (size_t)im * 16 * EMBD + kc);
        }
#pragma unroll
        for (int in = 0; in < 2; ++in) {
            b_h[in] = *(const short8*)(bh0 + (size_t)in * 16 * EMBD + kc);
            b_l[in] = *(const short8*)(bl0 + (size_t)in * 16 * EMBD + kc);
        }
#pragma unroll
        for (int im = 0; im < 2; ++im)
#pragma unroll
            for (int in = 0; in < 2; ++in) {
                acc[im][in] = __builtin_amdgcn_mfma_f32_16x16x32_bf16(a_h[im], b_h[in], acc[im][in], 0, 0, 0);
                acc[im][in] = __builtin_amdgcn_mfma_f32_16x16x32_bf16(a_h[im], b_l[in], acc[im][in], 0, 0, 0);
                acc[im][in] = __builtin_amdgcn_mfma_f32_16x16x32_bf16(a_l[im], b_h[in], acc[im][in], 0, 0, 0);
            }
    }
    const int qr = (lane >> 4) << 2;
#pragma unroll
    for (int im = 0; im < 2; ++im)
#pragma unroll
        for (int in = 0; in < 2; ++in) {
            int n = n0 + wn * 32 + in * 16 + fr;
            float bv = bias[n];
#pragma unroll
            for (int r = 0; r < 4; ++r) {
                int m = m0 + wm * 32 + im * 16 + qr + r;
                out[(size_t)m * EMBD + n] = acc[im][in][r] + bv;
            }
        }
}

extern "C" void kernel_launch(void* const* d_in, const int* in_sizes, int n_in,
                              void* d_out, int out_size, void* d_ws, size_t ws_size,
                              hipStream_t stream)
{
    const float* x    = (const float*)d_in[0];
    const float* vec  = (const float*)d_in[1];
    const float* Wqkv = (const float*)d_in[2];
    const float* bqkv = (const float*)d_in[3];
    const float* Wb   = (const float*)d_in[4];
    const float* bb   = (const float*)d_in[5];
    const float* Wout = (const float*)d_in[6];
    const float* bout = (const float*)d_in[7];
    float* out = (float*)d_out;

    char* ws = (char*)d_ws;
    u16*   qkvb  = (u16*)(ws);                      //  6,291,456
    u16*   Vt    = (u16*)(ws + 6291456);            //  2,097,152
    float* zpart = (float*)(ws + 8388608);          //    262,144 (4 z)
    float* bpart = (float*)(ws + 8650752);          // 16,777,216 (4 z f32)
    u16*   yh    = (u16*)(ws + 25427968);           //  2,097,152
    u16*   yl    = (u16*)(ws + 27525120);           //  2,097,152
    u16*   woth  = (u16*)(ws + 29622272);           //    524,288 (persistent)
    u16*   wotl  = (u16*)(ws + 30146560);           //    524,288
    char*  big   = ws + 30670848;                   // 67,108,864 shared region
    // big region lifetimes (sequenced by launch order):
    u16*   xh    = (u16*)(big);                     // prep -> gemm_qkv
    u16*   xl    = (u16*)(big + 2097152);
    u16*   wth   = (u16*)(big + 4194304);
    u16*   wtl   = (u16*)(big + 5767168);
    u16*   bm    = (u16*)(big);                     // bias_mat -> biasv
    u16*   nump  = (u16*)(big);                     // flash -> combine (8.4MB)
    // total: 97,779,712 B

    prep<<<1280, 256, 0, stream>>>(x, Wqkv, Wout, xh, xl, wth, wtl, woth, wotl);
    gemm_qkv_mfma<<<dim3(24, 32), 256, 0, stream>>>(xh, xl, wth, wtl, bqkv, qkvb, Vt);
    bias_mat<<<2080, 256, 0, stream>>>(vec, Wb, bb, bm);
    biasv_mfma<<<dim3(32, 8, 4), 256, 0, stream>>>(bm, Vt, bpart);
    flash_attn<<<dim3(32, 8, 4), 256, 0, stream>>>(qkvb, Vt, nump, zpart);
    combine_emit<<<1024, 256, 0, stream>>>(nump, zpart, bpart, yh, yl);
    gemm_out_mfma<<<dim3(8, 32), 256, 0, stream>>>(yh, yl, woth, wotl, bout, out);
}

// Round 12
// 276.332 us; speedup vs baseline: 1.0292x; 1.0200x over previous
//
#include <hip/hip_runtime.h>
#include <hip/hip_bf16.h>
#include <math.h>

#define NT 2048
#define EMBD 512
#define NH 8
#define QKV_LD 1536

typedef unsigned short u16;
typedef __attribute__((ext_vector_type(8))) short short8;
typedef __attribute__((ext_vector_type(4))) float v4f;

static __device__ __forceinline__ float bf2f(unsigned int u) {
    union { unsigned int i; float f; } c; c.i = u << 16; return c.f;
}
static __device__ __forceinline__ unsigned int f2bf(float x) {   // RNE
    union { float f; unsigned int u; } c; c.f = x;
    return (c.u + 0x7fffu + ((c.u >> 16) & 1u)) >> 16;
}

// ------- split+transpose one 64x64 tile of W into Wt[n][k] hi/lo ------------
static __device__ __forceinline__ void split_wt_tile(const float* __restrict__ W,
    u16* __restrict__ wth, u16* __restrict__ wtl, int ld, int n0, int k0, int t,
    float (*tile)[65])
{
    const int r = t >> 2, c4 = (t & 3) << 4;
#pragma unroll
    for (int j = 0; j < 4; ++j)
        *(float4*)&tile[r][c4 + (j << 2)] =
            *(const float4*)(W + (size_t)(k0 + r) * ld + n0 + c4 + (j << 2));
    __syncthreads();
    const int n_l = t >> 2;
    u16 th[16], tl[16];
#pragma unroll
    for (int j = 0; j < 16; ++j) {
        float f = tile[c4 + j][n_l];
        unsigned int h = f2bf(f);
        th[j] = (u16)h;
        tl[j] = (u16)f2bf(f - bf2f(h));
    }
    u16* dh = wth + (size_t)(n0 + n_l) * EMBD + k0 + c4;
    u16* dl = wtl + (size_t)(n0 + n_l) * EMBD + k0 + c4;
    *(uint4*)dh       = *(uint4*)&th[0];
    *(uint4*)(dh + 8) = *(uint4*)&th[8];
    *(uint4*)dl       = *(uint4*)&tl[0];
    *(uint4*)(dl + 8) = *(uint4*)&tl[8];
}

// ------- launch 1: x-split (0..1023), Wqkv^T (1024..1215), Wout^T
//         (1216..1279), bias_mat triangle tiles (1280..3359) ----------------
__global__ __launch_bounds__(256) void prep_bias(const float* __restrict__ x,
    const float* __restrict__ Wqkv, const float* __restrict__ Wout,
    const float* __restrict__ vec, const float* __restrict__ Wb,
    const float* __restrict__ bb,
    u16* __restrict__ xh, u16* __restrict__ xl,
    u16* __restrict__ wth, u16* __restrict__ wtl,
    u16* __restrict__ woth, u16* __restrict__ wotl,
    u16* __restrict__ bm)
{
    __shared__ __align__(16) char smem[22080];
    const int b = blockIdx.x, t = threadIdx.x;
    if (b < 1024) {
        int i = (b * 256 + t) << 2;
        float4 v = *(const float4*)(x + i);
        float f[4] = {v.x, v.y, v.z, v.w};
        unsigned int hi[4], lo[4];
#pragma unroll
        for (int j = 0; j < 4; ++j) {
            hi[j] = f2bf(f[j]);
            lo[j] = f2bf(f[j] - bf2f(hi[j]));
        }
        uint2 wh; wh.x = hi[0] | (hi[1] << 16); wh.y = hi[2] | (hi[3] << 16);
        uint2 wl; wl.x = lo[0] | (lo[1] << 16); wl.y = lo[2] | (lo[3] << 16);
        *(uint2*)(xh + i) = wh;
        *(uint2*)(xl + i) = wl;
        return;
    }
    if (b < 1216) {
        int bb2 = b - 1024;                    // 24 x 8
        split_wt_tile(Wqkv, wth, wtl, QKV_LD, (bb2 % 24) << 6, (bb2 / 24) << 6,
                      t, (float(*)[65])smem);
        return;
    }
    if (b < 1280) {
        int bb2 = b - 1216;                    // 8 x 8
        split_wt_tile(Wout, woth, wotl, EMBD, (bb2 & 7) << 6, (bb2 >> 3) << 6,
                      t, (float(*)[65])smem);
        return;
    }
    // ---- bias_mat path (frozen numerics) ----
    float* flds   = (float*)(smem);            // 32 f
    float* vql    = (float*)(smem + 128);      // 96 f
    float* vkl    = (float*)(smem + 512);      // 96 f
    float* bbl    = (float*)(smem + 896);      // 8 f
    float* ang    = (float*)(smem + 928);      // 1057 f
    u16*   biaslu = (u16*)(smem + 5156);       // 8*1057 u16

    int bi = b - 1280, tq = 0, rem = 64;
    while (bi >= rem) { bi -= rem; ++tq; --rem; }
    const int tk = tq + bi;
    const int q0 = tq << 5, k0 = tk << 5;

    if (t < 32) flds[t] = __fdiv_rn(__fdiv_rn((float)t, 31.0f), 0.1f);
    else if (t < 128) vql[t - 32] = vec[q0 * 3 + (t - 32)];
    else if (t < 224) vkl[t - 128] = vec[k0 * 3 + (t - 128)];
    else if (t < 232) bbl[t - 224] = bb[t - 224];
    __syncthreads();

    {   // angles
        const int qq = t & 31, kb = (t >> 5) << 2;
        const float a0 = vql[qq * 3], a1 = vql[qq * 3 + 1], a2 = vql[qq * 3 + 2];
#pragma unroll
        for (int j = 0; j < 4; ++j) {
            const int kk = kb + j;
            float c0 = vkl[kk * 3], c1 = vkl[kk * 3 + 1], c2 = vkl[kk * 3 + 2];
            float dot = __fadd_rn(__fadd_rn(__fmul_rn(a0, c0), __fmul_rn(a1, c1)),
                                  __fmul_rn(a2, c2));
            float dotc = fminf(fmaxf(dot, 0.0f), 1.0f);
            ang[qq * 33 + kk] = __fdiv_rn(acosf(dotc), 0.001f);
        }
    }
    __syncthreads();

    {   // sincos features -> MFMA projection (+bb via acc init)
        const int w = t >> 6, lane = t & 63;
        const int fr = lane & 15, kd = (lane >> 4) << 3, qr = (lane >> 4) << 2;
        short8 BS, BC;
#pragma unroll
        for (int j = 0; j < 8; ++j) {
            float ws = (fr < 8) ? Wb[(kd + j) * 8 + fr] : 0.0f;
            float wc = (fr < 8) ? Wb[(32 + kd + j) * 8 + fr] : 0.0f;
            BS[j] = (short)f2bf(ws);
            BC[j] = (short)f2bf(wc);
        }
        const float bb0 = (fr < 8) ? bbl[fr] : 0.0f;
        for (int tt = w; tt < 64; tt += 4) {
            int p = (tt << 4) + fr;
            float angv = ang[(p >> 5) * 33 + (p & 31)];
            short8 AS, AC;
#pragma unroll
            for (int j = 0; j < 8; ++j) {
                float ph = __fmul_rn(flds[kd + j], angv);
                float rv = ph * 0.15915494309189535f;
                float rf = rv - floorf(rv);
                AS[j] = (short)f2bf(__builtin_amdgcn_sinf(rf));
                AC[j] = (short)f2bf(__builtin_amdgcn_cosf(rf));
            }
            v4f c = {bb0, bb0, bb0, bb0};
            c = __builtin_amdgcn_mfma_f32_16x16x32_bf16(AS, BS, c, 0, 0, 0);
            c = __builtin_amdgcn_mfma_f32_16x16x32_bf16(AC, BC, c, 0, 0, 0);
            if (fr < 8) {
#pragma unroll
                for (int r = 0; r < 4; ++r) {
                    int pp = (tt << 4) + qr + r;
                    biaslu[fr * 1057 + (pp >> 5) * 33 + (pp & 31)] = (u16)f2bf(c[r]);
                }
            }
        }
    }
    __syncthreads();

    // store both orientations, coalesced uint2
    const int row = t >> 3, c4 = (t & 7) << 2;
#pragma unroll
    for (int h = 0; h < 8; ++h) {
        unsigned int o[4];
#pragma unroll
        for (int j = 0; j < 4; ++j)
            o[j] = biaslu[h * 1057 + row * 33 + c4 + j];
        uint2 wv; wv.x = o[0] | (o[1] << 16); wv.y = o[2] | (o[3] << 16);
        *(uint2*)(bm + ((size_t)h * NT + q0 + row) * NT + k0 + c4) = wv;
    }
    if (tk != tq) {
#pragma unroll
        for (int h = 0; h < 8; ++h) {
            unsigned int o[4];
#pragma unroll
            for (int j = 0; j < 4; ++j)
                o[j] = biaslu[h * 1057 + (c4 + j) * 33 + row];
            uint2 wv; wv.x = o[0] | (o[1] << 16); wv.y = o[2] | (o[3] << 16);
            *(uint2*)(bm + ((size_t)h * NT + k0 + row) * NT + q0 + c4) = wv;
        }
    }
}

// ------- qkv = x @ Wqkv + b (split bf16 MFMA); V-tiles routed to Vt ---------
__global__ __launch_bounds__(256) void gemm_qkv_mfma(const u16* __restrict__ xh,
    const u16* __restrict__ xl, const u16* __restrict__ wth,
    const u16* __restrict__ wtl, const float* __restrict__ bias,
    u16* __restrict__ qkvb, u16* __restrict__ Vt)
{
    __shared__ u16 vtile[64][72];
    const int bn = blockIdx.x;
    const int n0 = bn << 6, m0 = blockIdx.y << 6;
    const int t = threadIdx.x;
    const int w = t >> 6, lane = t & 63;
    const int wm = w >> 1, wn = w & 1;
    const int fr = lane & 15, kd = (lane >> 4) << 3;

    const u16* ah0 = xh + (size_t)(m0 + wm * 32 + fr) * EMBD + kd;
    const u16* al0 = xl + (size_t)(m0 + wm * 32 + fr) * EMBD + kd;
    const u16* bh0 = wth + (size_t)(n0 + wn * 32 + fr) * EMBD + kd;
    const u16* bl0 = wtl + (size_t)(n0 + wn * 32 + fr) * EMBD + kd;

    v4f acc[2][2] = {};
    for (int kc = 0; kc < EMBD; kc += 32) {
        short8 a_h[2], a_l[2], b_h[2], b_l[2];
#pragma unroll
        for (int im = 0; im < 2; ++im) {
            a_h[im] = *(const short8*)(ah0 + (size_t)im * 16 * EMBD + kc);
            a_l[im] = *(const short8*)(al0 + (size_t)im * 16 * EMBD + kc);
        }
#pragma unroll
        for (int in = 0; in < 2; ++in) {
            b_h[in] = *(const short8*)(bh0 + (size_t)in * 16 * EMBD + kc);
            b_l[in] = *(const short8*)(bl0 + (size_t)in * 16 * EMBD + kc);
        }
#pragma unroll
        for (int im = 0; im < 2; ++im)
#pragma unroll
            for (int in = 0; in < 2; ++in) {
                acc[im][in] = __builtin_amdgcn_mfma_f32_16x16x32_bf16(a_h[im], b_h[in], acc[im][in], 0, 0, 0);
                acc[im][in] = __builtin_amdgcn_mfma_f32_16x16x32_bf16(a_h[im], b_l[in], acc[im][in], 0, 0, 0);
                acc[im][in] = __builtin_amdgcn_mfma_f32_16x16x32_bf16(a_l[im], b_h[in], acc[im][in], 0, 0, 0);
            }
    }
    const int qr = (lane >> 4) << 2;
    if (bn % 3 != 2) {
#pragma unroll
        for (int im = 0; im < 2; ++im)
#pragma unroll
            for (int in = 0; in < 2; ++in) {
                int n = n0 + wn * 32 + in * 16 + fr;
                float bv = bias[n];
#pragma unroll
                for (int r = 0; r < 4; ++r) {
                    int m = m0 + wm * 32 + im * 16 + qr + r;
                    qkvb[(size_t)m * QKV_LD + n] = (u16)f2bf(acc[im][in][r] + bv);
                }
            }
    } else {
        const int h = bn / 3;
#pragma unroll
        for (int im = 0; im < 2; ++im)
#pragma unroll
            for (int in = 0; in < 2; ++in) {
                int nl = wn * 32 + in * 16 + fr;
                float bv = bias[n0 + nl];
#pragma unroll
                for (int r = 0; r < 4; ++r)
                    vtile[wm * 32 + im * 16 + qr + r][nl] =
                        (u16)f2bf(acc[im][in][r] + bv);
            }
        __syncthreads();
        const int c = t >> 2, kg = (t & 3) << 4;
        u16 tmp[16];
#pragma unroll
        for (int j = 0; j < 16; ++j) tmp[j] = vtile[kg + j][c];
        u16* dst = Vt + ((size_t)h * 64 + c) * NT + m0 + kg;
        *(uint4*)dst       = *(uint4*)&tmp[0];
        *(uint4*)(dst + 8) = *(uint4*)&tmp[8];
    }
}

// ------- launch 3: flash (blocks 0..1023, z=4, unroll-2 ILP) +
//         biasv (blocks 1024..1535, z=2) -------------------------------------
__global__ __launch_bounds__(256) void attn_fused(const u16* __restrict__ qkvb,
    const u16* __restrict__ Vt, const u16* __restrict__ bm,
    u16* __restrict__ nump, float* __restrict__ zpart,
    float* __restrict__ bpart)
{
    __shared__ u16 P[4][2][16][40];
    const int b = blockIdx.x, t = threadIdx.x;
    const int w = t >> 6, lane = t & 63;
    const int fr = lane & 15, kd = (lane >> 4) << 3, qr = (lane >> 4) << 2;
    if (b < 1024) {
        // ---- flash term: nump[z] = exp(QK/8)@V, zpart = exp rowsums ----
        const int qb = b & 31, h = (b >> 5) & 7, z = b >> 8;
        const int q0 = (qb << 6) + (w << 4);
        const int kbase = z << 9;

        const u16* qbp = qkvb + (size_t)(q0 + fr) * QKV_LD + h * 192 + kd;
        short8 qa0 = *(const short8*)(qbp);
        short8 qa1 = *(const short8*)(qbp + 32);
        const u16* kbp = qkvb + (size_t)kbase * QKV_LD + h * 192 + 64 + kd;
        const u16* vb  = Vt + ((size_t)h * 64 + fr) * NT + kbase + kd;

        v4f acc[4] = {};
        float zac[4] = {};
        for (int kt = 0; kt < 512; kt += 64) {
            short8 ka[4], kbv[4];
#pragma unroll
            for (int i = 0; i < 4; ++i) {
                const u16* kr = kbp + (size_t)(kt + i * 16 + fr) * QKV_LD;
                ka[i]  = *(const short8*)(kr);
                kbv[i] = *(const short8*)(kr + 32);
            }
            short8 vf[2][4];
#pragma unroll
            for (int ti = 0; ti < 4; ++ti) {
                vf[0][ti] = *(const short8*)(vb + (size_t)(ti * 16) * NT + kt);
                vf[1][ti] = *(const short8*)(vb + (size_t)(ti * 16) * NT + kt + 32);
            }
            v4f c[4];
#pragma unroll
            for (int i = 0; i < 4; ++i) {
                v4f cc = {};
                cc = __builtin_amdgcn_mfma_f32_16x16x32_bf16(qa0, ka[i], cc, 0, 0, 0);
                cc = __builtin_amdgcn_mfma_f32_16x16x32_bf16(qa1, kbv[i], cc, 0, 0, 0);
                c[i] = cc;
            }
#pragma unroll
            for (int i = 0; i < 4; ++i)
#pragma unroll
                for (int r = 0; r < 4; ++r) {
                    float ex = __expf(c[i][r] * 0.125f);
                    zac[r] += ex;
                    P[w][i >> 1][qr + r][((i & 1) << 4) + fr] = (u16)f2bf(ex);
                }
            union { uint2 u2[2]; short8 s8; } p0, p1;
            p0.u2[0] = *(uint2*)&P[w][0][fr][kd];
            p0.u2[1] = *(uint2*)&P[w][0][fr][kd + 4];
            p1.u2[0] = *(uint2*)&P[w][1][fr][kd];
            p1.u2[1] = *(uint2*)&P[w][1][fr][kd + 4];
#pragma unroll
            for (int ti = 0; ti < 4; ++ti) {
                acc[ti] = __builtin_amdgcn_mfma_f32_16x16x32_bf16(p0.s8, vf[0][ti], acc[ti], 0, 0, 0);
                acc[ti] = __builtin_amdgcn_mfma_f32_16x16x32_bf16(p1.s8, vf[1][ti], acc[ti], 0, 0, 0);
            }
        }
#pragma unroll
        for (int off = 1; off < 16; off <<= 1)
#pragma unroll
            for (int r = 0; r < 4; ++r) zac[r] += __shfl_xor(zac[r], off);
        if (fr == 0) {
#pragma unroll
            for (int r = 0; r < 4; ++r)
                zpart[((size_t)z * NH + h) * NT + q0 + qr + r] = zac[r];
        }
        u16* np = nump + (size_t)z * NT * EMBD;
#pragma unroll
        for (int ti = 0; ti < 4; ++ti)
#pragma unroll
            for (int r = 0; r < 4; ++r)
                np[(size_t)(q0 + qr + r) * EMBD + (h << 6) + (ti << 4) + fr] =
                    (u16)f2bf(acc[ti][r]);
    } else {
        // ---- biasv term: bpart[z] = bm @ V (split-K=2, 64-k unroll) ----
        const int b2 = b - 1024;
        const int qb = b2 & 31, h = (b2 >> 5) & 7, z = b2 >> 8;
        const int q0 = (qb << 6) + (w << 4);
        const int kbase = z << 10;

        const u16* arow  = bm + (size_t)(h * NT + q0 + fr) * NT + kbase + kd;
        const u16* vbase = Vt + ((size_t)h * 64 + fr) * NT + kbase + kd;

        v4f c[4] = {};
        for (int ks = 0; ks < 1024; ks += 64) {
            short8 a0 = *(const short8*)(arow + ks);
            short8 a1 = *(const short8*)(arow + ks + 32);
#pragma unroll
            for (int nt = 0; nt < 4; ++nt) {
                short8 b0 = *(const short8*)(vbase + (size_t)nt * 16 * NT + ks);
                short8 b1 = *(const short8*)(vbase + (size_t)nt * 16 * NT + ks + 32);
                c[nt] = __builtin_amdgcn_mfma_f32_16x16x32_bf16(a0, b0, c[nt], 0, 0, 0);
                c[nt] = __builtin_amdgcn_mfma_f32_16x16x32_bf16(a1, b1, c[nt], 0, 0, 0);
            }
        }
        float* bp = bpart + (size_t)z * NT * EMBD;
#pragma unroll
        for (int nt = 0; nt < 4; ++nt)
#pragma unroll
            for (int r = 0; r < 4; ++r)
                bp[(size_t)(q0 + qr + r) * EMBD + (h << 6) + (nt << 4) + fr] = c[nt][r];
    }
}

// ------- combine: y = (sum_z nump)/(sum_z zpart) + sum_z bpart -> yh/yl -----
__global__ __launch_bounds__(256) void combine_emit(const u16* __restrict__ nump,
    const float* __restrict__ zpart, const float* __restrict__ bpart,
    u16* __restrict__ yh, u16* __restrict__ yl)
{
    const int MN = NT * EMBD;
    int i = (blockIdx.x * 256 + threadIdx.x) << 2;
    const int q = i >> 9, h = (i & 511) >> 6;
    float zs = 0.f;
#pragma unroll
    for (int z = 0; z < 4; ++z) zs += zpart[((size_t)z * NH + h) * NT + q];
    const float inv = 1.0f / zs;
    float a[4] = {};
#pragma unroll
    for (int z = 0; z < 4; ++z) {
        uint2 r = *(const uint2*)(nump + (size_t)z * MN + i);
        a[0] += bf2f(r.x & 0xffffu); a[1] += bf2f(r.x >> 16);
        a[2] += bf2f(r.y & 0xffffu); a[3] += bf2f(r.y >> 16);
    }
    float bsum[4] = {};
#pragma unroll
    for (int z = 0; z < 2; ++z) {
        float4 p = *(const float4*)(bpart + (size_t)z * MN + i);
        bsum[0] += p.x; bsum[1] += p.y; bsum[2] += p.z; bsum[3] += p.w;
    }
    unsigned int hi[4], lo[4];
#pragma unroll
    for (int j = 0; j < 4; ++j) {
        float y = a[j] * inv + bsum[j];
        hi[j] = f2bf(y);
        lo[j] = f2bf(y - bf2f(hi[j]));
    }
    uint2 wh; wh.x = hi[0] | (hi[1] << 16); wh.y = hi[2] | (hi[3] << 16);
    uint2 wl; wl.x = lo[0] | (lo[1] << 16); wl.y = lo[2] | (lo[3] << 16);
    *(uint2*)(yh + i) = wh;
    *(uint2*)(yl + i) = wl;
}

// ------- out = y @ Wout + bout via split-precision bf16 MFMA ----------------
__global__ __launch_bounds__(256) void gemm_out_mfma(const u16* __restrict__ yh,
    const u16* __restrict__ yl, const u16* __restrict__ wh,
    const u16* __restrict__ wl, const float* __restrict__ bias,
    float* __restrict__ out)
{
    const int n0 = blockIdx.x << 6, m0 = blockIdx.y << 6;
    const int w = threadIdx.x >> 6, lane = threadIdx.x & 63;
    const int wm = w >> 1, wn = w & 1;
    const int fr = lane & 15, kd = (lane >> 4) << 3;

    const u16* ah0 = yh + (size_t)(m0 + wm * 32 + fr) * EMBD + kd;
    const u16* al0 = yl + (size_t)(m0 + wm * 32 + fr) * EMBD + kd;
    const u16* bh0 = wh + (size_t)(n0 + wn * 32 + fr) * EMBD + kd;
    const u16* bl0 = wl + (size_t)(n0 + wn * 32 + fr) * EMBD + kd;

    v4f acc[2][2] = {};
    for (int kc = 0; kc < EMBD; kc += 32) {
        short8 a_h[2], a_l[2], b_h[2], b_l[2];
#pragma unroll
        for (int im = 0; im < 2; ++im) {
            a_h[im] = *(const short8*)(ah0 + (size_t)im * 16 * EMBD + kc);
            a_l[im] = *(const short8*)(al0 + (size_t)im * 16 * EMBD + kc);
        }
#pragma unroll
        for (int in = 0; in < 2; ++in) {
            b_h[in] = *(const short8*)(bh0 + (size_t)in * 16 * EMBD + kc);
            b_l[in] = *(const short8*)(bl0 + (size_t)in * 16 * EMBD + kc);
        }
#pragma unroll
        for (int im = 0; im < 2; ++im)
#pragma unroll
            for (int in = 0; in < 2; ++in) {
                acc[im][in] = __builtin_amdgcn_mfma_f32_16x16x32_bf16(a_h[im], b_h[in], acc[im][in], 0, 0, 0);
                acc[im][in] = __builtin_amdgcn_mfma_f32_16x16x32_bf16(a_h[im], b_l[in], acc[im][in], 0, 0, 0);
                acc[im][in] = __builtin_amdgcn_mfma_f32_16x16x32_bf16(a_l[im], b_h[in], acc[im][in], 0, 0, 0);
            }
    }
    const int qr = (lane >> 4) << 2;
#pragma unroll
    for (int im = 0; im < 2; ++im)
#pragma unroll
        for (int in = 0; in < 2; ++in) {
            int n = n0 + wn * 32 + in * 16 + fr;
            float bv = bias[n];
#pragma unroll
            for (int r = 0; r < 4; ++r) {
                int m = m0 + wm * 32 + im * 16 + qr + r;
                out[(size_t)m * EMBD + n] = acc[im][in][r] + bv;
            }
        }
}

extern "C" void kernel_launch(void* const* d_in, const int* in_sizes, int n_in,
                              void* d_out, int out_size, void* d_ws, size_t ws_size,
                              hipStream_t stream)
{
    const float* x    = (const float*)d_in[0];
    const float* vec  = (const float*)d_in[1];
    const float* Wqkv = (const float*)d_in[2];
    const float* bqkv = (const float*)d_in[3];
    const float* Wb   = (const float*)d_in[4];
    const float* bb   = (const float*)d_in[5];
    const float* Wout = (const float*)d_in[6];
    const float* bout = (const float*)d_in[7];
    float* out = (float*)d_out;

    char* ws = (char*)d_ws;
    u16*   qkvb  = (u16*)(ws);                      //  6,291,456
    u16*   Vt    = (u16*)(ws + 6291456);            //  2,097,152
    float* zpart = (float*)(ws + 8388608);          //    262,144 (4 z)
    float* bpart = (float*)(ws + 8650752);          //  8,388,608 (2 z f32)
    u16*   yh    = (u16*)(ws + 17039360);           //  2,097,152
    u16*   yl    = (u16*)(ws + 19136512);           //  2,097,152
    u16*   woth  = (u16*)(ws + 21233664);           //    524,288
    u16*   wotl  = (u16*)(ws + 21757952);           //    524,288
    char*  trans = ws + 22282240;                   //  8,388,608 shared:
    u16*   xh    = (u16*)(trans);                   //   prep -> gemm_qkv
    u16*   xl    = (u16*)(trans + 2097152);
    u16*   wth   = (u16*)(trans + 4194304);
    u16*   wtl   = (u16*)(trans + 5767168);
    u16*   nump  = (u16*)(trans);                   //   attn_fused -> combine
    u16*   bm    = (u16*)(ws + 30670848);           // 67,108,864 (own region:
    // bias_mat runs concurrently with prep in launch 1)
    // total: 97,779,712 B

    prep_bias<<<3360, 256, 0, stream>>>(x, Wqkv, Wout, vec, Wb, bb,
                                        xh, xl, wth, wtl, woth, wotl, bm);
    gemm_qkv_mfma<<<dim3(24, 32), 256, 0, stream>>>(xh, xl, wth, wtl, bqkv, qkvb, Vt);
    attn_fused<<<1536, 256, 0, stream>>>(qkvb, Vt, bm, nump, zpart, bpart);
    combine_emit<<<1024, 256, 0, stream>>>(nump, zpart, bpart, yh, yl);
    gemm_out_mfma<<<dim3(8, 32), 256, 0, stream>>>(yh, yl, woth, wotl, bout, out);
}